// Round 1
// baseline (293.958 us; speedup 1.0000x reference)
//
#include <hip/hip_runtime.h>
#include <cstdint>
#include <cstddef>

typedef __bf16 bf16;
typedef __bf16 bf16x4 __attribute__((ext_vector_type(4)));
typedef __bf16 bf16x8 __attribute__((ext_vector_type(8)));
typedef float  f32x4  __attribute__((ext_vector_type(4)));

#define MDIM 2048
#define NDIM 4096
#define KDIM 4096
#define FLOATMAX 3.402823466e38f

// ---------------- fp32 -> bf16 conversion (grid-stride, float4 loads) ----------------
__global__ void cvt_f32_to_bf16(const float* __restrict__ src,
                                bf16* __restrict__ dst, int n4) {
    int i = blockIdx.x * blockDim.x + threadIdx.x;
    const int stride = gridDim.x * blockDim.x;
    for (; i < n4; i += stride) {
        f32x4 v = reinterpret_cast<const f32x4*>(src)[i];
        reinterpret_cast<bf16x4*>(dst)[i] = __builtin_convertvector(v, bf16x4);
    }
}

// async global->LDS, 16B per lane (HW: wave-uniform LDS base + lane*16)
__device__ __forceinline__ void g2lds16(const bf16* g, bf16* l) {
    __builtin_amdgcn_global_load_lds(
        (const __attribute__((address_space(1))) uint32_t*)g,
        (__attribute__((address_space(3))) uint32_t*)l, 16, 0, 0);
}

// ---------------- MAM main kernel ----------------
// Block tile 128(m) x 128(n); 512 threads = 8 waves in 2(m) x 4(n) grid;
// wave tile 64(m) x 32(n) = 4x2 MFMA tiles of 16x16.
// K handled as 2 splits x 32 iters x 2 ACCBLOCKs (BK=64 staged per iter).
__global__ __launch_bounds__(512, 2) void mam_kernel(
    const bf16* __restrict__ A,   // [M,K] bf16 (x)
    const bf16* __restrict__ B,   // [N,K] bf16 (weight, row n is column n of w)
    const float* __restrict__ bias,
    float* __restrict__ out)
{
    __shared__ __align__(16) bf16 sA0[128 * 32];
    __shared__ __align__(16) bf16 sA1[128 * 32];
    __shared__ __align__(16) bf16 sB0[128 * 32];
    __shared__ __align__(16) bf16 sB1[128 * 32];

    const int t    = threadIdx.x;
    const int lane = t & 63;
    const int w    = t >> 6;        // 0..7
    const int wm   = (w >> 2) * 64; // 0 or 64
    const int wn   = (w & 3) * 32;  // 0,32,64,96

    const int m0 = blockIdx.y * 128;
    const int n0 = blockIdx.x * 128;

    // staging: thread t loads 8 bf16 (16B); tile layout row-major [row][k], k-stride 32
    const int srow  = t >> 2;       // 0..127
    const int skoff = (t & 3) * 8;  // 0,8,16,24
    const bf16* gA = A + (size_t)(m0 + srow) * KDIM + skoff;
    const bf16* gB = B + (size_t)(n0 + srow) * KDIM + skoff;
    bf16* lA0 = &sA0[t * 8];
    bf16* lA1 = &sA1[t * 8];
    bf16* lB0 = &sB0[t * 8];
    bf16* lB1 = &sB1[t * 8];

    // fragment addressing (A: m=lane&15, k=(lane>>4)*8+j ; B symmetric with n=lane&15)
    const int frow = lane & 15;
    const int fk   = (lane >> 4) * 8;

    const f32x4 kZero = {0.f, 0.f, 0.f, 0.f};

    f32x4 acc[4][2];
#pragma unroll
    for (int i = 0; i < 4; ++i)
#pragma unroll
        for (int j = 0; j < 2; ++j) acc[i][j] = kZero;

#pragma unroll 1
    for (int split = 0; split < 2; ++split) {
        f32x4 mx[4][2], mn[4][2];
#pragma unroll
        for (int i = 0; i < 4; ++i)
#pragma unroll
            for (int j = 0; j < 2; ++j) {
                mx[i][j] = (f32x4)(-FLOATMAX);
                mn[i][j] = (f32x4)(FLOATMAX);
            }

        const bf16* gAs = gA + (size_t)split * 2048;  // split base along k
        const bf16* gBs = gB + (size_t)split * 2048;

#pragma unroll 1
        for (int bb = 0; bb < 32; ++bb) {
            __syncthreads();  // previous iter's LDS reads done
            const bf16* ga = gAs + (size_t)bb * 64;
            const bf16* gb = gBs + (size_t)bb * 64;
            g2lds16(ga,      lA0);   // ACCBLOCK 2*bb
            g2lds16(ga + 32, lA1);   // ACCBLOCK 2*bb+1
            g2lds16(gb,      lB0);
            g2lds16(gb + 32, lB1);
            __syncthreads();  // barrier drains vmcnt -> LDS tiles valid

            bf16x8 aF0[4], aF1[4], bF0[2], bF1[2];
#pragma unroll
            for (int i = 0; i < 4; ++i) {
                const int off = (wm + i * 16 + frow) * 32 + fk;
                aF0[i] = *(const bf16x8*)&sA0[off];
                aF1[i] = *(const bf16x8*)&sA1[off];
            }
#pragma unroll
            for (int j = 0; j < 2; ++j) {
                const int off = (wn + j * 16 + frow) * 32 + fk;
                bF0[j] = *(const bf16x8*)&sB0[off];
                bF1[j] = *(const bf16x8*)&sB1[off];
            }

#pragma unroll
            for (int i = 0; i < 4; ++i) {
#pragma unroll
                for (int j = 0; j < 2; ++j) {
                    f32x4 s0 = __builtin_amdgcn_mfma_f32_16x16x32_bf16(
                        aF0[i], bF0[j], kZero, 0, 0, 0);
                    f32x4 s1 = __builtin_amdgcn_mfma_f32_16x16x32_bf16(
                        aF1[i], bF1[j], kZero, 0, 0, 0);
#pragma unroll
                    for (int r = 0; r < 4; ++r) {
                        mx[i][j][r] = fmaxf(fmaxf(mx[i][j][r], s0[r]), s1[r]);  // max3 shape
                        mn[i][j][r] = fminf(fminf(mn[i][j][r], s0[r]), s1[r]);  // min3 shape
                    }
                }
            }
        }

#pragma unroll
        for (int i = 0; i < 4; ++i)
#pragma unroll
            for (int j = 0; j < 2; ++j)
                acc[i][j] += mx[i][j] + mn[i][j];
    }

    // epilogue: C/D layout col=lane&15, row=(lane>>4)*4+reg
    const int orow = (lane >> 4) * 4;
    const int ocol = lane & 15;
#pragma unroll
    for (int j = 0; j < 2; ++j) {
        const int col = n0 + wn + j * 16 + ocol;
        const float bv = bias[col];
#pragma unroll
        for (int i = 0; i < 4; ++i) {
            const int row = m0 + wm + i * 16 + orow;
#pragma unroll
            for (int r = 0; r < 4; ++r) {
                out[(size_t)(row + r) * NDIM + col] = acc[i][j][r] + bv;
            }
        }
    }
}

extern "C" void kernel_launch(void* const* d_in, const int* in_sizes, int n_in,
                              void* d_out, int out_size, void* d_ws, size_t ws_size,
                              hipStream_t stream) {
    const float* x    = (const float*)d_in[0];  // [M,K]
    const float* wgt  = (const float*)d_in[1];  // [N,K]
    const float* bias = (const float*)d_in[2];  // [N]
    float* out = (float*)d_out;

    bf16* xbf = (bf16*)d_ws;                        // M*K bf16 = 16 MiB
    bf16* wbf = xbf + (size_t)MDIM * KDIM;          // N*K bf16 = 32 MiB

    const int xn4 = (MDIM * KDIM) / 4;
    const int wn4 = (NDIM * KDIM) / 4;
    cvt_f32_to_bf16<<<dim3(2048), dim3(256), 0, stream>>>(x, xbf, xn4);
    cvt_f32_to_bf16<<<dim3(2048), dim3(256), 0, stream>>>(wgt, wbf, wn4);

    dim3 grid(NDIM / 128, MDIM / 128);  // (32, 16)
    mam_kernel<<<grid, dim3(512), 0, stream>>>(xbf, wbf, bias, out);
}

// Round 2
// 253.904 us; speedup vs baseline: 1.1578x; 1.1578x over previous
//
#include <hip/hip_runtime.h>
#include <cstdint>
#include <cstddef>

typedef __bf16 bf16;
typedef __bf16 bf16x4 __attribute__((ext_vector_type(4)));
typedef __bf16 bf16x8 __attribute__((ext_vector_type(8)));
typedef float  f32x4  __attribute__((ext_vector_type(4)));

#define MDIM 2048
#define NDIM 4096
#define KDIM 4096
#define FLOATMAX 3.402823466e38f

// ---------------- fp32 -> bf16 conversion (one launch for both tensors) ----------------
__global__ void cvt2_f32_to_bf16(const float* __restrict__ x, const float* __restrict__ w,
                                 bf16* __restrict__ xb, bf16* __restrict__ wb,
                                 int xn4, int wn4) {
    const int stride = gridDim.x * blockDim.x;
    int i = blockIdx.x * blockDim.x + threadIdx.x;
    for (int k = i; k < xn4; k += stride) {
        f32x4 v = reinterpret_cast<const f32x4*>(x)[k];
        reinterpret_cast<bf16x4*>(xb)[k] = __builtin_convertvector(v, bf16x4);
    }
    for (int k = i; k < wn4; k += stride) {
        f32x4 v = reinterpret_cast<const f32x4*>(w)[k];
        reinterpret_cast<bf16x4*>(wb)[k] = __builtin_convertvector(v, bf16x4);
    }
}

// async global->LDS, 16B per lane (HW: wave-uniform LDS base + lane*16)
__device__ __forceinline__ void g2lds16(const bf16* g, bf16* l) {
    __builtin_amdgcn_global_load_lds(
        (const __attribute__((address_space(1))) uint32_t*)g,
        (__attribute__((address_space(3))) uint32_t*)l, 16, 0, 0);
}

// ---------------- MAM main kernel ----------------
// Block tile 128(m) x 128(n); 512 threads = 8 waves in 2(m) x 4(n); wave tile 64x32.
// K: 64 stages of BK=64 (2 ACCBLOCKs each); split reset after stage 31 and 63.
// LDS double-buffered (64 KB): one barrier per stage, prefetch overlaps compute.
// Staging uses XOR chunk swizzle so fragment ds_read_b128 is 2-way conflict-free.
__global__ __launch_bounds__(512, 2) void mam_kernel(
    const bf16* __restrict__ A,   // [M,K] bf16 (x)
    const bf16* __restrict__ B,   // [N,K] bf16 (weight row n = col n of w)
    const float* __restrict__ bias,
    float* __restrict__ out)
{
    __shared__ __align__(16) bf16 sA[2][2][128 * 32];  // [parity][accblock-half]
    __shared__ __align__(16) bf16 sB[2][2][128 * 32];

    const int t    = threadIdx.x;
    const int lane = t & 63;
    const int w    = t >> 6;        // 0..7
    const int wm   = (w >> 2) * 64; // 0 or 64
    const int wn   = (w & 3) * 32;  // 0,32,64,96

    const int m0 = blockIdx.y * 128;
    const int n0 = blockIdx.x * 128;

    // staging: thread t -> row r=t>>2, slot p=t&3; fetches global chunk c = p ^ ((r>>1)&3)
    const int srow   = t >> 2;
    const int spos   = t & 3;
    const int schunk = spos ^ ((srow >> 1) & 3);
    const bf16* gA = A + (size_t)(m0 + srow) * KDIM + schunk * 8;
    const bf16* gB = B + (size_t)(n0 + srow) * KDIM + schunk * 8;
    const int ldst = t * 8;  // LDS dest: lane-contiguous 16B

    // fragment addressing: row R, chunk q=lane>>4 lives at slot q ^ ((R>>1)&3)
    const int frow = lane & 15;
    const int q    = lane >> 4;
    int offA[4], offB[2];
#pragma unroll
    for (int i = 0; i < 4; ++i) {
        const int R = wm + i * 16 + frow;
        offA[i] = R * 32 + (q ^ ((R >> 1) & 3)) * 8;
    }
#pragma unroll
    for (int j = 0; j < 2; ++j) {
        const int R = wn + j * 16 + frow;
        offB[j] = R * 32 + (q ^ ((R >> 1) & 3)) * 8;
    }

    const f32x4 kZero = {0.f, 0.f, 0.f, 0.f};

    f32x4 acc[4][2], mx[4][2], mn[4][2];
#pragma unroll
    for (int i = 0; i < 4; ++i)
#pragma unroll
        for (int j = 0; j < 2; ++j) {
            acc[i][j] = kZero;
            mx[i][j] = (f32x4)(-FLOATMAX);
            mn[i][j] = (f32x4)(FLOATMAX);
        }

    auto prefetch = [&](int s, int pb) {
        const bf16* ga = gA + (size_t)s * 64;
        const bf16* gb = gB + (size_t)s * 64;
        g2lds16(ga,      &sA[pb][0][ldst]);
        g2lds16(ga + 32, &sA[pb][1][ldst]);
        g2lds16(gb,      &sB[pb][0][ldst]);
        g2lds16(gb + 32, &sB[pb][1][ldst]);
    };

    auto compute = [&](int pb) {
        bf16x8 aF0[4], aF1[4], bF0[2], bF1[2];
#pragma unroll
        for (int i = 0; i < 4; ++i) {
            aF0[i] = *(const bf16x8*)&sA[pb][0][offA[i]];
            aF1[i] = *(const bf16x8*)&sA[pb][1][offA[i]];
        }
#pragma unroll
        for (int j = 0; j < 2; ++j) {
            bF0[j] = *(const bf16x8*)&sB[pb][0][offB[j]];
            bF1[j] = *(const bf16x8*)&sB[pb][1][offB[j]];
        }
#pragma unroll
        for (int i = 0; i < 4; ++i) {
#pragma unroll
            for (int j = 0; j < 2; ++j) {
                f32x4 s0 = __builtin_amdgcn_mfma_f32_16x16x32_bf16(
                    aF0[i], bF0[j], kZero, 0, 0, 0);
                f32x4 s1 = __builtin_amdgcn_mfma_f32_16x16x32_bf16(
                    aF1[i], bF1[j], kZero, 0, 0, 0);
#pragma unroll
                for (int r = 0; r < 4; ++r) {
                    mx[i][j][r] = fmaxf(fmaxf(mx[i][j][r], s0[r]), s1[r]);  // v_max3_f32
                    mn[i][j][r] = fminf(fminf(mn[i][j][r], s0[r]), s1[r]);  // v_min3_f32
                }
            }
        }
    };

    auto split_reset = [&]() {
#pragma unroll
        for (int i = 0; i < 4; ++i)
#pragma unroll
            for (int j = 0; j < 2; ++j) {
                acc[i][j] += mx[i][j] + mn[i][j];
                mx[i][j] = (f32x4)(-FLOATMAX);
                mn[i][j] = (f32x4)(FLOATMAX);
            }
    };

    prefetch(0, 0);

    int bb = 0;
#pragma unroll 1
    for (int it = 0; it < 32; ++it) {
        // even stage: compute parity 0, prefetch into parity 1 (bb even <= 62 -> bb+1 valid)
        __syncthreads();
        prefetch(bb + 1, 1);
        compute(0);
        ++bb;
        // odd stage: compute parity 1, prefetch into parity 0
        __syncthreads();
        if (bb < 63) prefetch(bb + 1, 0);
        compute(1);
        if (bb == 31 || bb == 63) split_reset();
        ++bb;
    }

    // epilogue: C/D layout col=lane&15, row=(lane>>4)*4+reg
    const int orow = (lane >> 4) * 4;
    const int ocol = lane & 15;
#pragma unroll
    for (int j = 0; j < 2; ++j) {
        const int col = n0 + wn + j * 16 + ocol;
        const float bv = bias[col];
#pragma unroll
        for (int i = 0; i < 4; ++i) {
            const int row = m0 + wm + i * 16 + orow;
#pragma unroll
            for (int r = 0; r < 4; ++r) {
                out[(size_t)(row + r) * NDIM + col] = acc[i][j][r] + bv;
            }
        }
    }
}

extern "C" void kernel_launch(void* const* d_in, const int* in_sizes, int n_in,
                              void* d_out, int out_size, void* d_ws, size_t ws_size,
                              hipStream_t stream) {
    const float* x    = (const float*)d_in[0];  // [M,K]
    const float* wgt  = (const float*)d_in[1];  // [N,K]
    const float* bias = (const float*)d_in[2];  // [N]
    float* out = (float*)d_out;

    bf16* xbf = (bf16*)d_ws;                        // M*K bf16 = 16 MiB
    bf16* wbf = xbf + (size_t)MDIM * KDIM;          // N*K bf16 = 32 MiB

    const int xn4 = (MDIM * KDIM) / 4;
    const int wn4 = (NDIM * KDIM) / 4;
    cvt2_f32_to_bf16<<<dim3(4096), dim3(256), 0, stream>>>(x, wgt, xbf, wbf, xn4, wn4);

    dim3 grid(NDIM / 128, MDIM / 128);  // (32, 16)
    mam_kernel<<<grid, dim3(512), 0, stream>>>(xbf, wbf, bias, out);
}